// Round 2
// baseline (7944.173 us; speedup 1.0000x reference)
//
#include <hip/hip_runtime.h>

typedef unsigned int u32;
typedef unsigned short u16;
typedef short bf16x8 __attribute__((ext_vector_type(8)));
typedef float f32x4 __attribute__((ext_vector_type(4)));

#define B_   4
#define S_   256
#define H_   512
#define GH_  2048
#define DIN_ 1024
#define M_   1024          // B*S
#define WG_PER_DIR 64      // scan workgroups per direction (32 gate-cols each)

__device__ __forceinline__ float bf2f(u16 u){
  union { u32 i; float f; } v; v.i = ((u32)u) << 16; return v.f;
}
__device__ __forceinline__ u16 f2bf(float f){
  union { float f; u32 i; } v; v.f = f;
  u32 r = v.i + 0x7fffu + ((v.i >> 16) & 1u);
  return (u16)(r >> 16);
}
__device__ __forceinline__ float sigm(float x){ return 1.f/(1.f + __expf(-x)); }
__device__ __forceinline__ float tanhfast(float x){
  float e = __expf(2.f*x); return 1.f - 2.f/(e + 1.f);   // == tanh(x)
}
// split 8 consecutive f32 into hi/lo bf16 fragments (RNE both halves)
__device__ __forceinline__ void split8(const float* __restrict__ p,
                                       bf16x8& h, bf16x8& l){
  #pragma unroll
  for (int j = 0; j < 8; ++j){
    float f = p[j];
    u16 hh = f2bf(f);
    h[j] = (short)hh;
    l[j] = (short)f2bf(f - bf2f(hh));
  }
}

// ---------------------------------------------------------------- embed
// x0 = concat(emb[sent], emb[pos]) -> hi/lo bf16 [1024][1024]
__global__ __launch_bounds__(256) void embed_kernel(
    const int* __restrict__ sent, const int* __restrict__ pos,
    const float* __restrict__ emb,
    u16* __restrict__ xhi, u16* __restrict__ xlo)
{
  const int m = blockIdx.x, tid = threadIdx.x;
  const int si = sent[m], pi = pos[m];
  const float2* es = (const float2*)(emb + (size_t)si * H_);
  const float2* ep = (const float2*)(emb + (size_t)pi * H_);
  float2 a = es[tid];
  float2 b = ep[tid];
  u32* xh = (u32*)(xhi + (size_t)m * DIN_);
  u32* xl = (u32*)(xlo + (size_t)m * DIN_);
  u16 ax = f2bf(a.x), ay = f2bf(a.y);
  u16 bx = f2bf(b.x), by = f2bf(b.y);
  xh[tid]       = (u32)ax | ((u32)ay << 16);
  xh[256 + tid] = (u32)bx | ((u32)by << 16);
  u16 axl = f2bf(a.x - bf2f(ax)), ayl = f2bf(a.y - bf2f(ay));
  u16 bxl = f2bf(b.x - bf2f(bx)), byl = f2bf(b.y - bf2f(by));
  xl[tid]       = (u32)axl | ((u32)ayl << 16);
  xl[256 + tid] = (u32)bxl | ((u32)byl << 16);
}

// ------------------------------------------------ GEMM: (xhi+xlo) . W^T
// C[m][n] = x[m][:] . Wrow(n)[koff:koff+K] + bias(n)   (all f32 except MFMA)
// W is f32; rows split hi/lo in-register; 3 MFMAs per frag pair (drop lo*lo).
// perm=1: n is gate-permuted (4*neuron+gate), Wrow = (n&3)*512 + (n>>2).
// grid = (N/64, M/64), block 256 (4 waves, each 32x32 via 2x2 16x16x32 frags)
__global__ __launch_bounds__(256,2) void gemm_x_w(
    const u16* __restrict__ xhi, const u16* __restrict__ xlo,
    const float* __restrict__ W, int ldw, int koff, int perm,
    const float* __restrict__ bias1, const float* __restrict__ bias2,
    float* __restrict__ C, int N, int K)
{
  const int lane = threadIdx.x & 63, wave = threadIdx.x >> 6;
  const int m0 = blockIdx.y*64 + (wave>>1)*32;
  const int n0 = blockIdx.x*64 + (wave&1)*32;
  const int r15 = lane & 15, quad = lane >> 4;
  const u16* a0 = xhi + (size_t)(m0 + r15)*K + quad*8;
  const u16* a1 = a0 + (size_t)16*K;
  const u16* l0 = xlo + (size_t)(m0 + r15)*K + quad*8;
  const u16* l1 = l0 + (size_t)16*K;
  const int nA = n0 + r15, nB = nA + 16;
  const int rA = perm ? ((nA&3)*H_ + (nA>>2)) : nA;
  const int rB = perm ? ((nB&3)*H_ + (nB>>2)) : nB;
  const float* b0 = W + (size_t)rA*ldw + koff + quad*8;
  const float* b1p = W + (size_t)rB*ldw + koff + quad*8;
  f32x4 acc00 = {0.f,0.f,0.f,0.f}, acc01 = acc00, acc10 = acc00, acc11 = acc00;
  for (int k = 0; k < K; k += 32){
    bf16x8 va0 = *(const bf16x8*)(a0 + k);
    bf16x8 va1 = *(const bf16x8*)(a1 + k);
    bf16x8 vl0 = *(const bf16x8*)(l0 + k);
    bf16x8 vl1 = *(const bf16x8*)(l1 + k);
    bf16x8 bh0, bl0, bh1, bl1;
    split8(b0 + k,  bh0, bl0);
    split8(b1p + k, bh1, bl1);
    acc00 = __builtin_amdgcn_mfma_f32_16x16x32_bf16(va0, bh0, acc00, 0,0,0);
    acc00 = __builtin_amdgcn_mfma_f32_16x16x32_bf16(vl0, bh0, acc00, 0,0,0);
    acc00 = __builtin_amdgcn_mfma_f32_16x16x32_bf16(va0, bl0, acc00, 0,0,0);
    acc01 = __builtin_amdgcn_mfma_f32_16x16x32_bf16(va0, bh1, acc01, 0,0,0);
    acc01 = __builtin_amdgcn_mfma_f32_16x16x32_bf16(vl0, bh1, acc01, 0,0,0);
    acc01 = __builtin_amdgcn_mfma_f32_16x16x32_bf16(va0, bl1, acc01, 0,0,0);
    acc10 = __builtin_amdgcn_mfma_f32_16x16x32_bf16(va1, bh0, acc10, 0,0,0);
    acc10 = __builtin_amdgcn_mfma_f32_16x16x32_bf16(vl1, bh0, acc10, 0,0,0);
    acc10 = __builtin_amdgcn_mfma_f32_16x16x32_bf16(va1, bl0, acc10, 0,0,0);
    acc11 = __builtin_amdgcn_mfma_f32_16x16x32_bf16(va1, bh1, acc11, 0,0,0);
    acc11 = __builtin_amdgcn_mfma_f32_16x16x32_bf16(vl1, bh1, acc11, 0,0,0);
    acc11 = __builtin_amdgcn_mfma_f32_16x16x32_bf16(va1, bl1, acc11, 0,0,0);
  }
  float bA = 0.f, bB = 0.f;
  if (bias1){ bA += bias1[rA]; bB += bias1[rB]; }
  if (bias2){ bA += bias2[rA]; bB += bias2[rB]; }
  const int mr = m0 + quad*4;
  #pragma unroll
  for (int r = 0; r < 4; ++r){
    C[(size_t)(mr + r)*N + nA]      = acc00[r] + bA;
    C[(size_t)(mr + r)*N + nB]      = acc01[r] + bB;
    C[(size_t)(mr + r + 16)*N + nA] = acc10[r] + bA;
    C[(size_t)(mr + r + 16)*N + nB] = acc11[r] + bB;
  }
}

// --------------------------- GEMM, W rows x activations, transposed out
// CT[b][h][t] = Wrow(h)[koff:] . x[(b*S+t)][:] + biasM[h]
// grid = (S/64, H/64, B), block 256
__global__ __launch_bounds__(256,2) void gemm_wT_x(
    const float* __restrict__ W, int ldw, int koff,
    const u16* __restrict__ xhi, const u16* __restrict__ xlo,
    const float* __restrict__ biasM,
    float* __restrict__ CT, int K)
{
  const int lane = threadIdx.x & 63, wave = threadIdx.x >> 6;
  const int m0 = blockIdx.y*64 + (wave>>1)*32;   // h index
  const int n0 = blockIdx.x*64 + (wave&1)*32;    // t index
  const int b  = blockIdx.z;
  const int r15 = lane & 15, quad = lane >> 4;
  const float* a0 = W + (size_t)(m0 + r15)*ldw + koff + quad*8;
  const float* a1 = a0 + (size_t)16*ldw;
  const u16* bh0 = xhi + (size_t)(b*S_ + n0 + r15)*DIN_ + quad*8;
  const u16* bh1 = bh0 + (size_t)16*DIN_;
  const u16* bl0 = xlo + (size_t)(b*S_ + n0 + r15)*DIN_ + quad*8;
  const u16* bl1 = bl0 + (size_t)16*DIN_;
  f32x4 acc00 = {0.f,0.f,0.f,0.f}, acc01 = acc00, acc10 = acc00, acc11 = acc00;
  for (int k = 0; k < K; k += 32){
    bf16x8 ah0, al0, ah1, al1;
    split8(a0 + k, ah0, al0);
    split8(a1 + k, ah1, al1);
    bf16x8 vh0 = *(const bf16x8*)(bh0 + k);
    bf16x8 vh1 = *(const bf16x8*)(bh1 + k);
    bf16x8 vl0 = *(const bf16x8*)(bl0 + k);
    bf16x8 vl1 = *(const bf16x8*)(bl1 + k);
    acc00 = __builtin_amdgcn_mfma_f32_16x16x32_bf16(ah0, vh0, acc00, 0,0,0);
    acc00 = __builtin_amdgcn_mfma_f32_16x16x32_bf16(al0, vh0, acc00, 0,0,0);
    acc00 = __builtin_amdgcn_mfma_f32_16x16x32_bf16(ah0, vl0, acc00, 0,0,0);
    acc01 = __builtin_amdgcn_mfma_f32_16x16x32_bf16(ah0, vh1, acc01, 0,0,0);
    acc01 = __builtin_amdgcn_mfma_f32_16x16x32_bf16(al0, vh1, acc01, 0,0,0);
    acc01 = __builtin_amdgcn_mfma_f32_16x16x32_bf16(ah0, vl1, acc01, 0,0,0);
    acc10 = __builtin_amdgcn_mfma_f32_16x16x32_bf16(ah1, vh0, acc10, 0,0,0);
    acc10 = __builtin_amdgcn_mfma_f32_16x16x32_bf16(al1, vh0, acc10, 0,0,0);
    acc10 = __builtin_amdgcn_mfma_f32_16x16x32_bf16(ah1, vl0, acc10, 0,0,0);
    acc11 = __builtin_amdgcn_mfma_f32_16x16x32_bf16(ah1, vh1, acc11, 0,0,0);
    acc11 = __builtin_amdgcn_mfma_f32_16x16x32_bf16(al1, vh1, acc11, 0,0,0);
    acc11 = __builtin_amdgcn_mfma_f32_16x16x32_bf16(ah1, vl1, acc11, 0,0,0);
  }
  const int mr = m0 + quad*4;
  const int nA = n0 + r15, nB = nA + 16;
  #pragma unroll
  for (int r = 0; r < 4; ++r){
    float bia0 = biasM[mr + r];
    float bia1 = biasM[mr + r + 16];
    CT[(size_t)(b*H_ + mr + r)*S_ + nA]      = acc00[r] + bia0;
    CT[(size_t)(b*H_ + mr + r)*S_ + nB]      = acc01[r] + bia0;
    CT[(size_t)(b*H_ + mr + r + 16)*S_ + nA] = acc10[r] + bia1;
    CT[(size_t)(b*H_ + mr + r + 16)*S_ + nB] = acc11[r] + bia1;
  }
}

// ---------------------------------------------------------------- scan
// Persistent bidirectional LSTM layer. 128 WGs x 128 thr: WG 0-63 fwd,
// 64-127 bwd; each WG owns 32 gate-permuted columns (w_hh hi+lo bf16 in
// 64KB LDS). Each wave owns one 16-col tile = 4 neurons x 4 batches.
// h carried in f32; enters MFMA as hi/lo bf16 split (A rows 0-3 hi(b),
// 4-7 lo(b), 8-15 zero). Per-step per-direction device barrier.
__global__ __launch_bounds__(128) void lstm_scan(
    const float* __restrict__ pre,   // [2][1024][2048] gate-permuted, +bias
    const float* __restrict__ whh,   // this layer: [2][2048][512] f32
    const int* __restrict__ length,  // [4]
    u16* __restrict__ Abuf,          // [2][2][16][512] bf16 (zeroed)
    u32* __restrict__ ctr,           // [2] (zeroed)
    u16* __restrict__ xhi, u16* __restrict__ xlo)  // [1024][1024]
{
  const int wg = blockIdx.x;
  const int dir = wg >> 6, lwg = wg & 63;
  const int tid = threadIdx.x, lane = tid & 63, wave = tid >> 6;  // 2 waves
  __shared__ uint4 wbh[2048];   // 32 rows x 64 chunks(16B), swizzled — hi
  __shared__ uint4 wbl[2048];   //                                    — lo
  const float* wsrc = whh + (size_t)dir*GH_*H_;
  #pragma unroll
  for (int it = 0; it < 16; ++it){
    int q = tid + 128*it;                 // 0..2047
    int rr = q >> 6, c = q & 63;
    int gp = lwg*32 + rr;
    int srow = (gp & 3)*H_ + (gp >> 2);   // un-permute: gate*512 + neuron
    const float* p = wsrc + (size_t)srow*H_ + c*8;
    bf16x8 h8, l8;
    split8(p, h8, l8);
    int idx = rr*64 + (c ^ (rr & 7));
    wbh[idx] = *(uint4*)&h8;
    wbl[idx] = *(uint4*)&l8;
  }
  __syncthreads();

  const int tile = lwg*2 + wave;              // 0..127 per direction
  const int gpbase = tile*16;
  const int r15 = lane & 15, quad = lane >> 4;
  const int wrow = wave*16 + r15;             // 0..31
  const int wrow64 = wrow*64, swz = wrow & 7;
  const float* preD = pre + (size_t)dir*M_*GH_;
  const int myb = lane & 3;
  const int njg = tile*4 + ((lane >> 2) & 3);
  const int lenb = length[myb];
  const int base = lane & ~3;
  u16* AbufD = Abuf + (size_t)dir*2*16*H_;
  float h_state = 0.f, c_state = 0.f;

  for (int ss = 0; ss < S_; ++ss){
    const int s = dir ? (S_ - 1 - ss) : ss;
    const int rp = ss & 1;
    const u16* Ar = AbufD + (size_t)rp*16*H_;
    f32x4 acc = {0.f,0.f,0.f,0.f};
    #pragma unroll
    for (int kk = 0; kk < 16; ++kk){
      bf16x8 va  = *(const bf16x8*)(Ar + (size_t)r15*H_ + kk*32 + quad*8);
      bf16x8 vbh = *(const bf16x8*)&wbh[wrow64 + ((kk*4 + quad) ^ swz)];
      bf16x8 vbl = *(const bf16x8*)&wbl[wrow64 + ((kk*4 + quad) ^ swz)];
      acc = __builtin_amdgcn_mfma_f32_16x16x32_bf16(va, vbh, acc, 0,0,0);
      acc = __builtin_amdgcn_mfma_f32_16x16x32_bf16(va, vbl, acc, 0,0,0);
    }
    // combine hi+lo A-rows, gather the 4 gates of my neuron
    float si = 0.f, sf = 0.f, sg = 0.f, so = 0.f;
    #pragma unroll
    for (int r = 0; r < 4; ++r){
      float gsum = acc[r] + __shfl(acc[r], lane ^ 16);
      float gpre = gsum + preD[(size_t)(r*S_ + s)*GH_ + gpbase + r15];
      float xi = __shfl(gpre, base + 0);
      float xf = __shfl(gpre, base + 1);
      float xg = __shfl(gpre, base + 2);
      float xo = __shfl(gpre, base + 3);
      if (r == myb){ si = xi; sf = xf; sg = xg; so = xo; }
    }
    float ctn = sigm(sf)*c_state + sigm(si)*tanhfast(sg);
    float htn = sigm(so)*tanhfast(ctn);
    const bool mk = (s < lenb);
    if (mk){ c_state = ctn; h_state = htn; }
    const float outv = mk ? htn : 0.f;
    if (lane < 16){
      u16* Aw = AbufD + (size_t)(rp^1)*16*H_;
      u16 hhi = f2bf(h_state);
      u16 hlo = f2bf(h_state - bf2f(hhi));
      Aw[(size_t)myb*H_ + njg]     = hhi;
      Aw[(size_t)(4+myb)*H_ + njg] = hlo;
      u16 ohi = f2bf(outv);
      u16 olo = f2bf(outv - bf2f(ohi));
      size_t xoff = (size_t)(myb*S_ + s)*DIN_ + dir*H_ + njg;
      xhi[xoff] = ohi;
      xlo[xoff] = olo;
    }
    // per-direction device barrier: release -> arrive -> spin -> acquire
    __threadfence();
    __syncthreads();
    if (tid == 0){
      const u32 target = (u32)(ss + 1)*WG_PER_DIR;
      atomicAdd(&ctr[dir], 1u);
      while (__hip_atomic_load(&ctr[dir], __ATOMIC_RELAXED,
                               __HIP_MEMORY_SCOPE_AGENT) < target){
        __builtin_amdgcn_s_sleep(1);
      }
    }
    __syncthreads();
    __threadfence();
  }
}

// ---------------------------------------------------------------- score
// out[b,s,t] = b2 + sum_h w2[h]*tanh(pa[b,s,h] + pbT[b,h,t])   (f32)
// (b1 already folded into pbT)
__global__ __launch_bounds__(256) void score_kernel(
    const float* __restrict__ pa, const float* __restrict__ pbT,
    const float* __restrict__ w2, const float* __restrict__ b2,
    float* __restrict__ out)
{
  const int bs = blockIdx.x;
  const int b = bs >> 8;
  const int t = threadIdx.x;
  __shared__ float pas[H_];
  __shared__ float w2s[H_];
  const float* paRow = pa + (size_t)bs*H_;
  for (int i = t; i < H_; i += 256){ pas[i] = paRow[i]; w2s[i] = w2[i]; }
  __syncthreads();
  const float* pbB = pbT + (size_t)b*H_*S_ + t;
  float acc = b2[0];
  #pragma unroll 4
  for (int h = 0; h < H_; ++h){
    float v = pas[h] + pbB[(size_t)h*S_];
    acc += w2s[h]*tanhfast(v);
  }
  out[(size_t)bs*S_ + t] = acc;
}

// ---------------------------------------------------------------- launch
extern "C" void kernel_launch(void* const* d_in, const int* in_sizes, int n_in,
                              void* d_out, int out_size, void* d_ws, size_t ws_size,
                              hipStream_t stream)
{
  const int*   sent = (const int*)d_in[0];
  const int*   pos  = (const int*)d_in[1];
  const int*   len  = (const int*)d_in[2];
  const float* emb  = (const float*)d_in[3];
  const float* wih  = (const float*)d_in[4];
  const float* whh  = (const float*)d_in[5];
  const float* bih  = (const float*)d_in[6];
  const float* bhh  = (const float*)d_in[7];
  const float* w1   = (const float*)d_in[8];
  const float* b1   = (const float*)d_in[9];
  const float* w2   = (const float*)d_in[10];
  const float* b2   = (const float*)d_in[11];
  float* out = (float*)d_out;

  char* ws = (char*)d_ws;
  u16*   Abuf = (u16*)(ws);                        // 64 KB
  u32*   ctr  = (u32*)(ws + 65536);                // 64 B
  u16*   x0hi = (u16*)(ws + ((size_t)1<<20));      // 2 MB each
  u16*   x0lo = (u16*)(ws + ((size_t)3<<20));
  u16*   x1hi = (u16*)(ws + ((size_t)5<<20));
  u16*   x1lo = (u16*)(ws + ((size_t)7<<20));
  u16*   x2hi = (u16*)(ws + ((size_t)9<<20));
  u16*   x2lo = (u16*)(ws + ((size_t)11<<20));
  float* pa   = (float*)(ws + ((size_t)13<<20));   // 2 MB
  float* pbT  = (float*)(ws + ((size_t)15<<20));   // 2 MB
  float* pre  = (float*)(ws + ((size_t)17<<20));   // 16 MB [2][1024][2048]

  embed_kernel<<<dim3(M_), dim3(256), 0, stream>>>(sent, pos, emb, x0hi, x0lo);

  for (int l = 0; l < 2; ++l){
    const u16* xh = l ? x1hi : x0hi;
    const u16* xl = l ? x1lo : x0lo;
    for (int d = 0; d < 2; ++d){
      gemm_x_w<<<dim3(GH_/64, M_/64), dim3(256), 0, stream>>>(
        xh, xl, wih + (size_t)(l*2+d)*GH_*DIN_, DIN_, 0, 1,
        bih + (size_t)(l*2+d)*GH_, bhh + (size_t)(l*2+d)*GH_,
        pre + (size_t)d*M_*GH_, GH_, DIN_);
    }
    hipMemsetAsync(Abuf, 0, 65536 + 64, stream);   // Abuf + barrier counters
    u16* oh = l ? x2hi : x1hi;
    u16* ol = l ? x2lo : x1lo;
    lstm_scan<<<dim3(2*WG_PER_DIR), dim3(128), 0, stream>>>(
        pre, whh + (size_t)l*2*GH_*H_, len, Abuf, ctr, oh, ol);
  }

  // pa[b,s,h] = x . wa^T   (wa = w1[:, :1024]), no bias
  gemm_x_w<<<dim3(H_/64, M_/64), dim3(256), 0, stream>>>(
      x2hi, x2lo, w1, GH_, 0, 0, nullptr, nullptr, pa, H_, DIN_);
  // pbT[b,h,t] = x . wb^T + b1   (wb = w1[:, 1024:])
  gemm_wT_x<<<dim3(S_/64, H_/64, B_), dim3(256), 0, stream>>>(
      w1, GH_, DIN_, x2hi, x2lo, b1, pbT, DIN_);
  score_kernel<<<dim3(M_), dim3(256), 0, stream>>>(pa, pbT, w2, b2, out);
}

// Round 3
// 3118.067 us; speedup vs baseline: 2.5478x; 2.5478x over previous
//
#include <hip/hip_runtime.h>

typedef unsigned int u32;
typedef unsigned short u16;
typedef unsigned long long u64;
typedef short bf16x8 __attribute__((ext_vector_type(8)));
typedef float f32x4 __attribute__((ext_vector_type(4)));

#define B_   4
#define S_   256
#define H_   512
#define GH_  2048
#define DIN_ 1024
#define M_   1024          // B*S
#define WG_PER_DIR 64      // scan workgroups per direction (32 gate-cols each)

__device__ __forceinline__ float bf2f(u16 u){
  union { u32 i; float f; } v; v.i = ((u32)u) << 16; return v.f;
}
__device__ __forceinline__ u16 f2bf(float f){
  union { float f; u32 i; } v; v.f = f;
  u32 r = v.i + 0x7fffu + ((v.i >> 16) & 1u);
  return (u16)(r >> 16);
}
__device__ __forceinline__ float sigm(float x){ return 1.f/(1.f + __expf(-x)); }
__device__ __forceinline__ float tanhfast(float x){
  float e = __expf(2.f*x); return 1.f - 2.f/(e + 1.f);   // == tanh(x)
}
// split 8 consecutive f32 into hi/lo bf16 fragments (RNE both halves)
__device__ __forceinline__ void split8(const float* __restrict__ p,
                                       bf16x8& h, bf16x8& l){
  #pragma unroll
  for (int j = 0; j < 8; ++j){
    float f = p[j];
    u16 hh = f2bf(f);
    h[j] = (short)hh;
    l[j] = (short)f2bf(f - bf2f(hh));
  }
}

// ------------------------------------------------------- weight pre-split
// src: n4 float4's -> hi/lo bf16 arrays (u64-packed stores)
__global__ __launch_bounds__(256) void split_w(
    const float* __restrict__ src, u16* __restrict__ hi, u16* __restrict__ lo,
    int n4)
{
  int i = blockIdx.x*256 + threadIdx.x;
  if (i >= n4) return;
  float4 f = ((const float4*)src)[i];
  u16 h0 = f2bf(f.x), h1 = f2bf(f.y), h2 = f2bf(f.z), h3 = f2bf(f.w);
  u16 l0 = f2bf(f.x - bf2f(h0)), l1 = f2bf(f.y - bf2f(h1));
  u16 l2 = f2bf(f.z - bf2f(h2)), l3 = f2bf(f.w - bf2f(h3));
  ((u64*)hi)[i] = (u64)h0 | ((u64)h1<<16) | ((u64)h2<<32) | ((u64)h3<<48);
  ((u64*)lo)[i] = (u64)l0 | ((u64)l1<<16) | ((u64)l2<<32) | ((u64)l3<<48);
}

// ---------------------------------------------------------------- embed
// x0 = concat(emb[sent], emb[pos]) -> hi/lo bf16 [1024][1024]
__global__ __launch_bounds__(256) void embed_kernel(
    const int* __restrict__ sent, const int* __restrict__ pos,
    const float* __restrict__ emb,
    u16* __restrict__ xhi, u16* __restrict__ xlo)
{
  const int m = blockIdx.x, tid = threadIdx.x;
  const int si = sent[m], pi = pos[m];
  const float2* es = (const float2*)(emb + (size_t)si * H_);
  const float2* ep = (const float2*)(emb + (size_t)pi * H_);
  float2 a = es[tid];
  float2 b = ep[tid];
  u32* xh = (u32*)(xhi + (size_t)m * DIN_);
  u32* xl = (u32*)(xlo + (size_t)m * DIN_);
  u16 ax = f2bf(a.x), ay = f2bf(a.y);
  u16 bx = f2bf(b.x), by = f2bf(b.y);
  xh[tid]       = (u32)ax | ((u32)ay << 16);
  xh[256 + tid] = (u32)bx | ((u32)by << 16);
  u16 axl = f2bf(a.x - bf2f(ax)), ayl = f2bf(a.y - bf2f(ay));
  u16 bxl = f2bf(b.x - bf2f(bx)), byl = f2bf(b.y - bf2f(by));
  xl[tid]       = (u32)axl | ((u32)ayl << 16);
  xl[256 + tid] = (u32)bxl | ((u32)byl << 16);
}

// ---------------------------------------- GEMM, pre-split bf16 both sides
// C[m][n] = (Ah+Al)[m][:] . (Bh+Bl)row(n)[:] + bias(n); 3 MFMAs (drop lo*lo)
// perm=1: row(n) = (n&3)*512 + (n>>2) (gate-permute)
// grid = (N/64, M/64), block 256 (4 waves, each 32x32 via 2x2 16x16x32)
__global__ __launch_bounds__(256,2) void gemm_bf16(
    const u16* __restrict__ Ah, const u16* __restrict__ Al,
    const u16* __restrict__ Bh, const u16* __restrict__ Bl, int ldb, int perm,
    const float* __restrict__ bias1, const float* __restrict__ bias2,
    float* __restrict__ C, int N, int K)
{
  const int lane = threadIdx.x & 63, wave = threadIdx.x >> 6;
  const int m0 = blockIdx.y*64 + (wave>>1)*32;
  const int n0 = blockIdx.x*64 + (wave&1)*32;
  const int r15 = lane & 15, quad = lane >> 4;
  const u16* a0 = Ah + (size_t)(m0 + r15)*K + quad*8;
  const u16* a1 = a0 + (size_t)16*K;
  const u16* l0 = Al + (size_t)(m0 + r15)*K + quad*8;
  const u16* l1 = l0 + (size_t)16*K;
  const int nA = n0 + r15, nB = nA + 16;
  const int rA = perm ? ((nA&3)*H_ + (nA>>2)) : nA;
  const int rB = perm ? ((nB&3)*H_ + (nB>>2)) : nB;
  const u16* bh0 = Bh + (size_t)rA*ldb + quad*8;
  const u16* bh1 = Bh + (size_t)rB*ldb + quad*8;
  const u16* bl0 = Bl + (size_t)rA*ldb + quad*8;
  const u16* bl1 = Bl + (size_t)rB*ldb + quad*8;
  f32x4 acc00 = {0.f,0.f,0.f,0.f}, acc01 = acc00, acc10 = acc00, acc11 = acc00;
  for (int k = 0; k < K; k += 32){
    bf16x8 va0 = *(const bf16x8*)(a0 + k);
    bf16x8 va1 = *(const bf16x8*)(a1 + k);
    bf16x8 vl0 = *(const bf16x8*)(l0 + k);
    bf16x8 vl1 = *(const bf16x8*)(l1 + k);
    bf16x8 wh0 = *(const bf16x8*)(bh0 + k);
    bf16x8 wh1 = *(const bf16x8*)(bh1 + k);
    bf16x8 wl0v = *(const bf16x8*)(bl0 + k);
    bf16x8 wl1v = *(const bf16x8*)(bl1 + k);
    acc00 = __builtin_amdgcn_mfma_f32_16x16x32_bf16(va0, wh0, acc00, 0,0,0);
    acc00 = __builtin_amdgcn_mfma_f32_16x16x32_bf16(vl0, wh0, acc00, 0,0,0);
    acc00 = __builtin_amdgcn_mfma_f32_16x16x32_bf16(va0, wl0v, acc00, 0,0,0);
    acc01 = __builtin_amdgcn_mfma_f32_16x16x32_bf16(va0, wh1, acc01, 0,0,0);
    acc01 = __builtin_amdgcn_mfma_f32_16x16x32_bf16(vl0, wh1, acc01, 0,0,0);
    acc01 = __builtin_amdgcn_mfma_f32_16x16x32_bf16(va0, wl1v, acc01, 0,0,0);
    acc10 = __builtin_amdgcn_mfma_f32_16x16x32_bf16(va1, wh0, acc10, 0,0,0);
    acc10 = __builtin_amdgcn_mfma_f32_16x16x32_bf16(vl1, wh0, acc10, 0,0,0);
    acc10 = __builtin_amdgcn_mfma_f32_16x16x32_bf16(va1, wl0v, acc10, 0,0,0);
    acc11 = __builtin_amdgcn_mfma_f32_16x16x32_bf16(va1, wh1, acc11, 0,0,0);
    acc11 = __builtin_amdgcn_mfma_f32_16x16x32_bf16(vl1, wh1, acc11, 0,0,0);
    acc11 = __builtin_amdgcn_mfma_f32_16x16x32_bf16(va1, wl1v, acc11, 0,0,0);
  }
  float bA = 0.f, bB = 0.f;
  if (bias1){ bA += bias1[rA]; bB += bias1[rB]; }
  if (bias2){ bA += bias2[rA]; bB += bias2[rB]; }
  const int mr = m0 + quad*4;
  #pragma unroll
  for (int r = 0; r < 4; ++r){
    C[(size_t)(mr + r)*N + nA]      = acc00[r] + bA;
    C[(size_t)(mr + r)*N + nB]      = acc01[r] + bB;
    C[(size_t)(mr + r + 16)*N + nA] = acc10[r] + bA;
    C[(size_t)(mr + r + 16)*N + nB] = acc11[r] + bB;
  }
}

// --------------------------- GEMM, pre-split W rows x activations, C^T out
// CT[b][h][t] = (Wh+Wl)row(h)[:] . (xh+xl)[(b*S+t)][:] + biasM[h]
// grid = (S/64, H/64, B), block 256
__global__ __launch_bounds__(256,2) void gemm_wT_x(
    const u16* __restrict__ Wh, const u16* __restrict__ Wl, int ldw,
    const u16* __restrict__ xh, const u16* __restrict__ xl,
    const float* __restrict__ biasM,
    float* __restrict__ CT, int K)
{
  const int lane = threadIdx.x & 63, wave = threadIdx.x >> 6;
  const int m0 = blockIdx.y*64 + (wave>>1)*32;   // h index
  const int n0 = blockIdx.x*64 + (wave&1)*32;    // t index
  const int b  = blockIdx.z;
  const int r15 = lane & 15, quad = lane >> 4;
  const u16* ah0 = Wh + (size_t)(m0 + r15)*ldw + quad*8;
  const u16* ah1 = ah0 + (size_t)16*ldw;
  const u16* al0 = Wl + (size_t)(m0 + r15)*ldw + quad*8;
  const u16* al1 = al0 + (size_t)16*ldw;
  const u16* bh0 = xh + (size_t)(b*S_ + n0 + r15)*DIN_ + quad*8;
  const u16* bh1 = bh0 + (size_t)16*DIN_;
  const u16* bl0 = xl + (size_t)(b*S_ + n0 + r15)*DIN_ + quad*8;
  const u16* bl1 = bl0 + (size_t)16*DIN_;
  f32x4 acc00 = {0.f,0.f,0.f,0.f}, acc01 = acc00, acc10 = acc00, acc11 = acc00;
  for (int k = 0; k < K; k += 32){
    bf16x8 vah0 = *(const bf16x8*)(ah0 + k);
    bf16x8 vah1 = *(const bf16x8*)(ah1 + k);
    bf16x8 val0 = *(const bf16x8*)(al0 + k);
    bf16x8 val1 = *(const bf16x8*)(al1 + k);
    bf16x8 vh0 = *(const bf16x8*)(bh0 + k);
    bf16x8 vh1 = *(const bf16x8*)(bh1 + k);
    bf16x8 vl0 = *(const bf16x8*)(bl0 + k);
    bf16x8 vl1 = *(const bf16x8*)(bl1 + k);
    acc00 = __builtin_amdgcn_mfma_f32_16x16x32_bf16(vah0, vh0, acc00, 0,0,0);
    acc00 = __builtin_amdgcn_mfma_f32_16x16x32_bf16(val0, vh0, acc00, 0,0,0);
    acc00 = __builtin_amdgcn_mfma_f32_16x16x32_bf16(vah0, vl0, acc00, 0,0,0);
    acc01 = __builtin_amdgcn_mfma_f32_16x16x32_bf16(vah0, vh1, acc01, 0,0,0);
    acc01 = __builtin_amdgcn_mfma_f32_16x16x32_bf16(val0, vh1, acc01, 0,0,0);
    acc01 = __builtin_amdgcn_mfma_f32_16x16x32_bf16(vah0, vl1, acc01, 0,0,0);
    acc10 = __builtin_amdgcn_mfma_f32_16x16x32_bf16(vah1, vh0, acc10, 0,0,0);
    acc10 = __builtin_amdgcn_mfma_f32_16x16x32_bf16(val1, vh0, acc10, 0,0,0);
    acc10 = __builtin_amdgcn_mfma_f32_16x16x32_bf16(vah1, vl0, acc10, 0,0,0);
    acc11 = __builtin_amdgcn_mfma_f32_16x16x32_bf16(vah1, vh1, acc11, 0,0,0);
    acc11 = __builtin_amdgcn_mfma_f32_16x16x32_bf16(val1, vh1, acc11, 0,0,0);
    acc11 = __builtin_amdgcn_mfma_f32_16x16x32_bf16(vah1, vl1, acc11, 0,0,0);
  }
  const int mr = m0 + quad*4;
  const int nA = n0 + r15, nB = nA + 16;
  #pragma unroll
  for (int r = 0; r < 4; ++r){
    float bia0 = biasM[mr + r];
    float bia1 = biasM[mr + r + 16];
    CT[(size_t)(b*H_ + mr + r)*S_ + nA]      = acc00[r] + bia0;
    CT[(size_t)(b*H_ + mr + r)*S_ + nB]      = acc01[r] + bia0;
    CT[(size_t)(b*H_ + mr + r + 16)*S_ + nA] = acc10[r] + bia1;
    CT[(size_t)(b*H_ + mr + r + 16)*S_ + nB] = acc11[r] + bia1;
  }
}

// ---------------------------------------------------------------- scan
// Persistent bidirectional LSTM layer, FENCE-FREE coherent protocol.
// 128 WGs x 128 thr: WG 0-63 fwd, 64-127 bwd; wave owns 16 gate-permuted
// cols (4 neurons x 4 batches). w_hh fragments preloaded into VGPRs
// (hi+lo bf16, ~128 VGPRs) — no LDS at all. h-exchange: packed u32
// relaxed AGENT-scope atomics (sc0 sc1 -> Infinity Cache; no wbl2/inv).
// Ordering via __syncthreads' vmcnt(0) drain + counter atomicAdd.
// A layout: [dir][2 bufs][8 rows][256 u32]; rows 0-3 hi(b), 4-7 lo(b);
// u32 packs col pair (2p, 2p+1). h in f32 regs, hi/lo split into A.
__global__ __launch_bounds__(128,1) void lstm_scan(
    const float* __restrict__ pre,   // [2][1024][2048] gate-permuted, +bias
    const float* __restrict__ whh,   // this layer: [2][2048][512] f32
    const int* __restrict__ length,  // [4]
    u32* __restrict__ Au32,          // [2][2][8][256] u32 (zeroed)
    u32* __restrict__ ctr,           // [2] (zeroed)
    u32* __restrict__ xh32, u32* __restrict__ xl32)  // [1024][512] u32
{
  const int wg = blockIdx.x;
  const int dir = wg >> 6, lwg = wg & 63;
  const int tid = threadIdx.x, lane = tid & 63, wave = tid >> 6;  // 2 waves
  const int r15 = lane & 15, quad = lane >> 4;
  const int tile = lwg*2 + wave;              // 0..127 per direction
  const int gpbase = tile*16;

  // ---- preload w_hh fragments into registers (one-time)
  const float* wdir = whh + (size_t)dir*GH_*H_;
  const int gp = gpbase + r15;                // gate-permuted col owned as B row
  const int srow = (gp & 3)*H_ + (gp >> 2);   // un-permute: gate*512 + neuron
  bf16x8 wh[16], wl[16];
  #pragma unroll
  for (int kk = 0; kk < 16; ++kk)
    split8(wdir + (size_t)srow*H_ + kk*32 + quad*8, wh[kk], wl[kk]);

  const float* preD = pre + (size_t)dir*M_*GH_;
  const int myb = lane & 3;
  const int njg = tile*4 + ((lane >> 2) & 3);
  const int lenb = length[myb];
  const int base = lane & ~3;
  const int row = r15 & 7;                    // rows 8-15 duplicate 0-7 (C rows 8-15 unused)
  u32* AbufD = Au32 + dir*4096;
  float h_state = 0.f, c_state = 0.f;

  for (int ss = 0; ss < S_; ++ss){
    const int s = dir ? (S_ - 1 - ss) : ss;
    const int rp = ss & 1;
    // ---- gather A fragments (coherent loads from MALL)
    const u64* Ar64 = (const u64*)(AbufD + rp*2048);
    union { u64 d[2]; bf16x8 v; } ua[16];
    #pragma unroll
    for (int kk = 0; kk < 16; ++kk){
      ua[kk].d[0] = __hip_atomic_load(Ar64 + (size_t)row*128 + kk*8 + quad*2,
                                      __ATOMIC_RELAXED, __HIP_MEMORY_SCOPE_AGENT);
      ua[kk].d[1] = __hip_atomic_load(Ar64 + (size_t)row*128 + kk*8 + quad*2 + 1,
                                      __ATOMIC_RELAXED, __HIP_MEMORY_SCOPE_AGENT);
    }
    f32x4 acc = {0.f,0.f,0.f,0.f};
    #pragma unroll
    for (int kk = 0; kk < 16; ++kk){
      acc = __builtin_amdgcn_mfma_f32_16x16x32_bf16(ua[kk].v, wh[kk], acc, 0,0,0);
      acc = __builtin_amdgcn_mfma_f32_16x16x32_bf16(ua[kk].v, wl[kk], acc, 0,0,0);
    }
    // ---- combine hi+lo A-rows, gather the 4 gates of my neuron
    float si = 0.f, sf = 0.f, sg = 0.f, so = 0.f;
    #pragma unroll
    for (int r = 0; r < 4; ++r){
      float gsum = acc[r] + __shfl(acc[r], lane ^ 16);
      float gpre = gsum + preD[(size_t)(r*S_ + s)*GH_ + gpbase + r15];
      float xi = __shfl(gpre, base + 0);
      float xf = __shfl(gpre, base + 1);
      float xg = __shfl(gpre, base + 2);
      float xo = __shfl(gpre, base + 3);
      if (r == myb){ si = xi; sf = xf; sg = xg; so = xo; }
    }
    float ctn = sigm(sf)*c_state + sigm(si)*tanhfast(sg);
    float htn = sigm(so)*tanhfast(ctn);
    const bool mk = (s < lenb);
    if (mk){ c_state = ctn; h_state = htn; }
    const float outv = mk ? htn : 0.f;
    // ---- pack col pairs via shuffle, store (Abuf coherent; xout normal)
    u32 hv = f2bf(h_state);
    u32 hl = f2bf(h_state - bf2f((u16)hv));
    u32 ov = f2bf(outv);
    u32 ol = f2bf(outv - bf2f((u16)ov));
    u32 ph  = (u32)__shfl((int)hv, lane ^ 4);
    u32 pl  = (u32)__shfl((int)hl, lane ^ 4);
    u32 po  = (u32)__shfl((int)ov, lane ^ 4);
    u32 pol = (u32)__shfl((int)ol, lane ^ 4);
    if (lane < 16){
      u32* Aw = AbufD + (rp^1)*2048;
      const int p = njg >> 1;                   // col-pair index 0..255
      const int xw = (myb*S_ + s)*(DIN_/2) + dir*(H_/2) + p;
      if ((lane & 4) == 0){                     // even col: hi words
        __hip_atomic_store(Aw + myb*256 + p, hv | (ph << 16),
                           __ATOMIC_RELAXED, __HIP_MEMORY_SCOPE_AGENT);
        xh32[xw] = ov | (po << 16);
      } else {                                  // odd col: lo words
        __hip_atomic_store(Aw + (4+myb)*256 + p, pl | (hl << 16),
                           __ATOMIC_RELAXED, __HIP_MEMORY_SCOPE_AGENT);
        xl32[xw] = pol | (ol << 16);
      }
    }
    // ---- per-direction device barrier (no fences; syncthreads drains vmcnt)
    __syncthreads();
    if (tid == 0){
      __hip_atomic_fetch_add(&ctr[dir], 1u,
                             __ATOMIC_RELAXED, __HIP_MEMORY_SCOPE_AGENT);
      const u32 target = (u32)(ss + 1)*WG_PER_DIR;
      while (__hip_atomic_load(&ctr[dir], __ATOMIC_RELAXED,
                               __HIP_MEMORY_SCOPE_AGENT) < target){
        __builtin_amdgcn_s_sleep(1);
      }
    }
    __syncthreads();
  }
}

// ---------------------------------------------------------------- score
// out[b,s,t] = b2 + sum_h w2[h]*tanh(pa[b,s,h] + pbT[b,h,t])   (f32)
__global__ __launch_bounds__(256) void score_kernel(
    const float* __restrict__ pa, const float* __restrict__ pbT,
    const float* __restrict__ w2, const float* __restrict__ b2,
    float* __restrict__ out)
{
  const int bs = blockIdx.x;
  const int b = bs >> 8;
  const int t = threadIdx.x;
  __shared__ float pas[H_];
  __shared__ float w2s[H_];
  const float* paRow = pa + (size_t)bs*H_;
  for (int i = t; i < H_; i += 256){ pas[i] = paRow[i]; w2s[i] = w2[i]; }
  __syncthreads();
  const float* pbB = pbT + (size_t)b*H_*S_ + t;
  float acc = b2[0];
  #pragma unroll 4
  for (int h = 0; h < H_; ++h){
    float v = pas[h] + pbB[(size_t)h*S_];
    acc += w2s[h]*tanhfast(v);
  }
  out[(size_t)bs*S_ + t] = acc;
}

// ---------------------------------------------------------------- launch
extern "C" void kernel_launch(void* const* d_in, const int* in_sizes, int n_in,
                              void* d_out, int out_size, void* d_ws, size_t ws_size,
                              hipStream_t stream)
{
  const int*   sent = (const int*)d_in[0];
  const int*   pos  = (const int*)d_in[1];
  const int*   len  = (const int*)d_in[2];
  const float* emb  = (const float*)d_in[3];
  const float* wih  = (const float*)d_in[4];
  const float* whh  = (const float*)d_in[5];
  const float* bih  = (const float*)d_in[6];
  const float* bhh  = (const float*)d_in[7];
  const float* w1   = (const float*)d_in[8];
  const float* b1   = (const float*)d_in[9];
  const float* w2   = (const float*)d_in[10];
  const float* b2   = (const float*)d_in[11];
  float* out = (float*)d_out;

  char* ws = (char*)d_ws;
  u32*   Au32  = (u32*)(ws);                        // 32 KB
  u32*   ctr   = (u32*)(ws + 32768);                // 64 B
  u16*   x0hi  = (u16*)(ws + ((size_t)1<<20));      // 2 MB each
  u16*   x0lo  = (u16*)(ws + ((size_t)3<<20));
  u16*   x1hi  = (u16*)(ws + ((size_t)5<<20));
  u16*   x1lo  = (u16*)(ws + ((size_t)7<<20));
  u16*   x2hi  = (u16*)(ws + ((size_t)9<<20));
  u16*   x2lo  = (u16*)(ws + ((size_t)11<<20));
  float* pa    = (float*)(ws + ((size_t)13<<20));   // 2 MB
  float* pbT   = (float*)(ws + ((size_t)15<<20));   // 2 MB
  float* pre   = (float*)(ws + ((size_t)17<<20));   // 16 MB [2][1024][2048]
  u16*   wihH  = (u16*)(ws + ((size_t)33<<20));     // 16 MB
  u16*   wihL  = (u16*)(ws + ((size_t)49<<20));     // 16 MB
  u16*   w1H   = (u16*)(ws + ((size_t)65<<20));     // 2 MB
  u16*   w1L   = (u16*)(ws + ((size_t)67<<20));     // 2 MB -> total 69 MB

  // one-time per call: pre-split weights into hi/lo bf16
  split_w<<<dim3(8192), dim3(256), 0, stream>>>(wih, wihH, wihL, 2097152);
  split_w<<<dim3(1024), dim3(256), 0, stream>>>(w1,  w1H,  w1L,   262144);

  embed_kernel<<<dim3(M_), dim3(256), 0, stream>>>(sent, pos, emb, x0hi, x0lo);

  for (int l = 0; l < 2; ++l){
    const u16* xh = l ? x1hi : x0hi;
    const u16* xl = l ? x1lo : x0lo;
    for (int d = 0; d < 2; ++d){
      const size_t wo = (size_t)(l*2+d)*GH_*DIN_;
      gemm_bf16<<<dim3(GH_/64, M_/64), dim3(256), 0, stream>>>(
        xh, xl, wihH + wo, wihL + wo, DIN_, 1,
        bih + (size_t)(l*2+d)*GH_, bhh + (size_t)(l*2+d)*GH_,
        pre + (size_t)d*M_*GH_, GH_, DIN_);
    }
    hipMemsetAsync(Au32, 0, 32768 + 64, stream);   // A buffers + barrier ctr
    u16* oh = l ? x2hi : x1hi;
    u16* ol = l ? x2lo : x1lo;
    lstm_scan<<<dim3(2*WG_PER_DIR), dim3(128), 0, stream>>>(
        pre, whh + (size_t)l*2*GH_*H_, len, Au32, ctr, (u32*)oh, (u32*)ol);
  }

  // pa[b,s,h] = x . wa^T   (wa = w1[:, :1024]), no bias
  gemm_bf16<<<dim3(H_/64, M_/64), dim3(256), 0, stream>>>(
      x2hi, x2lo, w1H, w1L, GH_, 0, nullptr, nullptr, pa, H_, DIN_);
  // pbT[b,h,t] = x . wb^T + b1   (wb = w1[:, 1024:])
  gemm_wT_x<<<dim3(S_/64, H_/64, B_), dim3(256), 0, stream>>>(
      w1H + DIN_, w1L + DIN_, GH_, x2hi, x2lo, b1, pbT, DIN_);
  score_kernel<<<dim3(M_), dim3(256), 0, stream>>>(pa, pbT, w2, b2, out);
}